// Round 3
// baseline (313.528 us; speedup 1.0000x reference)
//
#include <hip/hip_runtime.h>

typedef __attribute__((ext_vector_type(8))) short bfrag8;    // 8 bf16 (4 VGPRs)
typedef __attribute__((ext_vector_type(16))) float f32x16;   // 32x32 MFMA acc

#define B_ 16
#define C_ 64
#define H_ 128
#define W_ 128
#define E_ 4
#define HW_ (H_ * W_)

// ---- fast-path ws layout (bytes) ----
#define INT_ELEMS (16 * 130 * 130 * 64)
#define INT_BYTES (INT_ELEMS * 2)              // 34,611,200
#define WT_ELEMS (4 * 9 * 64 * 64)             // 147,456
#define OFF_WT   INT_BYTES
#define OFF_POOL (OFF_WT + WT_ELEMS * 2)
#define WS_NEEDED ((size_t)(OFF_POOL + 1024 * 4))

// ---- fallback ws layout (floats) ----
#define FB_WT_OFF 0
#define FB_POOLED_OFF 147456
#define FB_EW_OFF 148480

__device__ inline unsigned short f2bf(float f) {
    unsigned u = __builtin_bit_cast(unsigned, f);
    unsigned r = u + 0x7FFFu + ((u >> 16) & 1u);
    return (unsigned short)(r >> 16);
}

// ---------------- prep: wcvt + inT h-halos + pooled zero (one pass) ----------------
__global__ __launch_bounds__(256) void prep(const float* __restrict__ cw,
                                            unsigned short* __restrict__ wT,
                                            unsigned short* __restrict__ inT,
                                            float* __restrict__ pooled) {
    const int idx = blockIdx.x * 256 + threadIdx.x;
    if (idx < WT_ELEMS) {  // [e][co][ci][3][3] -> [e][tap][co][ci]
        const int ci = idx & 63;
        int r = idx >> 6;
        const int co = r & 63; r >>= 6;
        const int tap = r % 9;
        const int e = r / 9;
        wT[idx] = f2bf(cw[(((e * C_ + co) * C_ + ci) * 9) + tap]);
    }
    if (idx < 33280) {  // 16 img x 2 halo rows x 130 slots x 64ci, 16B chunks
        const int c16 = idx % 1040;
        const int r2 = idx / 1040;
        const int b = r2 >> 1;
        const int row = (r2 & 1) ? 129 : 0;
        float4* p = (float4*)(inT + ((size_t)(b * 130 + row) * 130) * 64) + c16;
        *p = make_float4(0.f, 0.f, 0.f, 0.f);
    }
    if (idx < 1024) pooled[idx] = 0.f;
}

// ---------------- tcvt_pool: NCHW fp32 -> padded NHWC bf16, fused mean-pool ----------------
__global__ __launch_bounds__(256) void tcvt_pool(const float* __restrict__ in,
                                                 unsigned short* __restrict__ inT,
                                                 float* __restrict__ pooled) {
    const int bid = blockIdx.x;          // 16 x 64 row-pairs
    const int b = bid >> 6;
    const int hp = bid & 63;
    const int t = threadIdx.x;
    const int h = hp * 2 + (t >> 7);
    const int w = t & 127;
    const int lane = t & 63;             // wave = one row-half, uniform h

    const float* src = in + ((size_t)b * C_ * H_ + h) * W_ + w;
    bfrag8 vv[8];
#pragma unroll
    for (int ci = 0; ci < 64; ++ci) {
        const float v = src[(size_t)ci * HW_];
        vv[ci >> 3][ci & 7] = (short)f2bf(v);
        float s = v;
#pragma unroll
        for (int off = 32; off; off >>= 1) s += __shfl_down(s, off);
        if (lane == 0) atomicAdd(&pooled[b * C_ + ci], s);
    }
    unsigned short* dst = inT + (((size_t)b * 130 + h + 1) * 130 + (w + 1)) * 64;
#pragma unroll
    for (int j = 0; j < 8; ++j) *(bfrag8*)(dst + (j << 3)) = vv[j];
    if (w == 0 || w == 127) {            // w-halo columns (x=0 / x=129)
        unsigned short* hp2 = dst + ((w == 0) ? -64 : 64);
        const bfrag8 z = {0, 0, 0, 0, 0, 0, 0, 0};
#pragma unroll
        for (int j = 0; j < 8; ++j) *(bfrag8*)(hp2 + (j << 3)) = z;
    }
}

// ---------------- conv: no-LDS implicit GEMM, fused gate ----------------
__global__ __launch_bounds__(256) void conv_direct(const float* __restrict__ in,
                                                   const float* __restrict__ kk,
                                                   const float* __restrict__ cb,
                                                   const float* __restrict__ gw,
                                                   const float* __restrict__ gb,
                                                   const float* __restrict__ pooled,
                                                   const unsigned short* __restrict__ inT,
                                                   const unsigned short* __restrict__ wT,
                                                   float* __restrict__ out) {
    const int raw = blockIdx.x;
    const int swz = (raw & 7) * 256 + (raw >> 3);   // XCD-bijective: img-pair per XCD
    const int b = swz >> 7;
    const int h0 = swz & 127;
    const int tid = threadIdx.x;
    const int lane = tid & 63;
    const int wv = tid >> 6;
    const int ln = lane & 31;
    const int lh = lane >> 5;

    // ---- gate (wave 0 recomputes; broadcast via LDS) ----
    __shared__ float sEW[E_];
    if (tid < 64) {
        const float p = pooled[b * C_ + lane] * (1.0f / (float)HW_);
        float part[E_];
#pragma unroll
        for (int e = 0; e < E_; e++) part[e] = p * gw[e * C_ + lane];
#pragma unroll
        for (int off = 32; off; off >>= 1)
#pragma unroll
            for (int e = 0; e < E_; e++) part[e] += __shfl_down(part[e], off);
        if (lane == 0) {
            float lg[E_];
#pragma unroll
            for (int e = 0; e < E_; e++) lg[e] = part[e] + gb[e];
            float m = fmaxf(fmaxf(lg[0], lg[1]), fmaxf(lg[2], lg[3]));
            float ex[E_], sum = 0.f;
#pragma unroll
            for (int e = 0; e < E_; e++) { ex[e] = __expf(lg[e] - m); sum += ex[e]; }
            float inv = 1.0f / sum;
            int i1 = 0;
            for (int e = 1; e < E_; e++) if (ex[e] > ex[i1]) i1 = e;
            int i2 = -1;
            for (int e = 0; e < E_; e++) {
                if (e == i1) continue;
                if (i2 < 0 || ex[e] > ex[i2]) i2 = e;
            }
#pragma unroll
            for (int e = 0; e < E_; e++)
                sEW[e] = (e == i1 || e == i2) ? ex[e] * inv : 0.f;
        }
    }
    __syncthreads();

    int e0 = 0, e1 = 0; float w0 = 0.f, w1 = 0.f;
    {
        int found = 0;
        for (int e = 0; e < E_; e++) {
            float we = sEW[e];
            if (we != 0.f) {
                if (!found) { e0 = e; w0 = we; found = 1; }
                else        { e1 = e; w1 = we; }
            }
        }
        if (w1 == 0.f) e1 = e0;
    }

    const int co0 = (wv >> 1) * 32;
    const int xh = (wv & 1) * 64;

    f32x16 acc00, acc01, acc10, acc11;
#pragma unroll
    for (int i = 0; i < 16; i++) { acc00[i] = 0.f; acc01[i] = 0.f; acc10[i] = 0.f; acc11[i] = 0.f; }

    // B operand straight from global: lane ln = pixel slot, 16B = 8 consecutive ci
    const unsigned short* binbase =
        inT + (((size_t)(b * 130 + h0)) * 130 + xh + ln) * 64 + (lh << 3);
    const unsigned short* wbase0 = wT + (((e0 * 9) * 64 + co0 + ln) << 6) + (lh << 3);
    const unsigned short* wbase1 = wT + (((e1 * 9) * 64 + co0 + ln) << 6) + (lh << 3);

    for (int ky = 0; ky < 3; ++ky) {
#pragma unroll
        for (int kx = 0; kx < 3; ++kx) {
            const int tap = ky * 3 + kx;
            const unsigned short* bp = binbase + ((ky * 130 + kx) << 6);
            const unsigned short* w0p = wbase0 + ((tap << 12));
            const unsigned short* w1p = wbase1 + ((tap << 12));
#pragma unroll
            for (int kb = 0; kb < 4; ++kb) {
                bfrag8 a0 = *(const bfrag8*)(w0p + (kb << 4));
                bfrag8 a1 = *(const bfrag8*)(w1p + (kb << 4));
                bfrag8 bA = *(const bfrag8*)(bp + (kb << 4));
                bfrag8 bB = *(const bfrag8*)(bp + (32 << 6) + (kb << 4));
                acc00 = __builtin_amdgcn_mfma_f32_32x32x16_bf16(a0, bA, acc00, 0, 0, 0);
                acc01 = __builtin_amdgcn_mfma_f32_32x32x16_bf16(a0, bB, acc01, 0, 0, 0);
                acc10 = __builtin_amdgcn_mfma_f32_32x32x16_bf16(a1, bA, acc10, 0, 0, 0);
                acc11 = __builtin_amdgcn_mfma_f32_32x32x16_bf16(a1, bB, acc11, 0, 0, 0);
            }
        }
    }

    // ---- epilogue: out = in + relu(acc+b)*k*w  (D: col=lane&31=px, row=co) ----
#pragma unroll
    for (int rg = 0; rg < 16; rg++) {
        const int co = co0 + (rg & 3) + 8 * (rg >> 2) + 4 * lh;
        const float kv = kk[b * C_ + co];
        const float f0 = kv * w0, f1 = kv * w1;
        const float bb0 = cb[e0 * C_ + co], bb1 = cb[e1 * C_ + co];
        const size_t rowbase = ((size_t)(b * C_ + co) * H_ + h0) * W_;
        {
            const int px = xh + ln;
            const float iv = in[rowbase + px];
            out[rowbase + px] = iv + fmaxf(acc00[rg] + bb0, 0.f) * f0
                                   + fmaxf(acc10[rg] + bb1, 0.f) * f1;
        }
        {
            const int px = xh + 32 + ln;
            const float iv = in[rowbase + px];
            out[rowbase + px] = iv + fmaxf(acc01[rg] + bb0, 0.f) * f0
                                   + fmaxf(acc11[rg] + bb1, 0.f) * f1;
        }
    }
}

// ================= fallback (fp32 path, used only if ws too small) =================
#define CHUNK 32

__global__ __launch_bounds__(256) void pool_kernel(const float* __restrict__ in,
                                                   float* __restrict__ pooled) {
    const int bc = blockIdx.x;
    const float* p = in + (size_t)bc * HW_;
    float s = 0.f;
    for (int i = threadIdx.x; i < HW_ / 4; i += 256) {
        float4 v = ((const float4*)p)[i];
        s += v.x + v.y + v.z + v.w;
    }
    for (int off = 32; off; off >>= 1) s += __shfl_down(s, off);
    __shared__ float red[4];
    const int lane = threadIdx.x & 63, wv = threadIdx.x >> 6;
    if (lane == 0) red[wv] = s;
    __syncthreads();
    if (threadIdx.x == 0)
        pooled[bc] = (red[0] + red[1] + red[2] + red[3]) * (1.0f / (float)HW_);
}

__global__ void gate_kernel(const float* __restrict__ pooled,
                            const float* __restrict__ gate_w,
                            const float* __restrict__ gate_b,
                            float* __restrict__ ew) {
    const int b = threadIdx.x;
    if (b >= B_) return;
    float lg[E_];
    for (int e = 0; e < E_; e++) {
        float s = gate_b[e];
        for (int c = 0; c < C_; c++) s += pooled[b * C_ + c] * gate_w[e * C_ + c];
        lg[e] = s;
    }
    float m = fmaxf(fmaxf(lg[0], lg[1]), fmaxf(lg[2], lg[3]));
    float ex[E_], sum = 0.f;
    for (int e = 0; e < E_; e++) { ex[e] = expf(lg[e] - m); sum += ex[e]; }
    for (int e = 0; e < E_; e++) ex[e] /= sum;
    int i1 = 0;
    for (int e = 1; e < E_; e++) if (ex[e] > ex[i1]) i1 = e;
    int i2 = -1;
    for (int e = 0; e < E_; e++) {
        if (e == i1) continue;
        if (i2 < 0 || ex[e] > ex[i2]) i2 = e;
    }
    for (int e = 0; e < E_; e++)
        ew[b * E_ + e] = (e == i1 || e == i2) ? ex[e] : 0.f;
}

__global__ __launch_bounds__(256) void wtr_kernel(const float* __restrict__ cw,
                                                  float* __restrict__ wT) {
    const int idx = blockIdx.x * 256 + threadIdx.x;
    if (idx >= E_ * C_ * 9 * C_) return;
    const int co = idx & 63;
    const int t2 = idx >> 6;
    const int tap = t2 % 9;
    const int t3 = t2 / 9;
    const int ci = t3 & 63;
    const int e = t3 >> 6;
    wT[idx] = cw[(((e * C_ + co) * C_ + ci) * 9) + tap];
}

__global__ __launch_bounds__(512) void conv_fallback(const float* __restrict__ in,
                                                     const float* __restrict__ kk,
                                                     const float* __restrict__ wT,
                                                     const float* __restrict__ cb,
                                                     const float* __restrict__ ew,
                                                     float* __restrict__ out) {
    const int bid = blockIdx.x;
    const int b = bid / H_;
    const int h = bid % H_;
    const int tid = threadIdx.x;
    const int lane = tid & 63;
    const int wv = tid >> 6;
    const int x0 = wv * 16;

    __shared__ float sIn[CHUNK * 3 * W_];

    float w0 = 0.f, w1 = 0.f;
    int e0 = 0, e1 = 0;
    {
        float we[E_];
#pragma unroll
        for (int e = 0; e < E_; e++) we[e] = ew[b * E_ + e];
        int found = 0;
        for (int e = 0; e < E_; e++) {
            if (we[e] != 0.f) {
                if (!found) { e0 = e; w0 = we[e]; found = 1; }
                else        { e1 = e; w1 = we[e]; }
            }
        }
        if (w1 == 0.f) e1 = e0;
    }

    float acc0[16], acc1[16];
#pragma unroll
    for (int i = 0; i < 16; i++) { acc0[i] = 0.f; acc1[i] = 0.f; }

    for (int cblk = 0; cblk < C_ / CHUNK; cblk++) {
        const int cbase = cblk * CHUNK;
        __syncthreads();
        for (int f = tid; f < CHUNK * 3 * W_ / 4; f += 512) {
            const int fi = f * 4;
            const int ci = fi / (3 * W_);
            const int rem = fi - ci * 3 * W_;
            const int kyy = rem / W_;
            const int x = rem - kyy * W_;
            const int hh = h + kyy - 1;
            float4 v = make_float4(0.f, 0.f, 0.f, 0.f);
            if (hh >= 0 && hh < H_)
                v = *(const float4*)(in + ((size_t)(b * C_ + cbase + ci) * H_ + hh) * W_ + x);
            *(float4*)(sIn + fi) = v;
        }
        __syncthreads();

        const float* wp0 = wT + (size_t)((e0 * C_ + cbase) * 9) * C_ + lane;
        const float* wp1 = wT + (size_t)((e1 * C_ + cbase) * 9) * C_ + lane;
        for (int ci = 0; ci < CHUNK; ci++) {
            float wa[9], wb[9];
#pragma unroll
            for (int t = 0; t < 9; t++) {
                wa[t] = wp0[(ci * 9 + t) * C_];
                wb[t] = wp1[(ci * 9 + t) * C_];
            }
            const float* rowp = sIn + ci * 3 * W_;
#pragma unroll
            for (int kyy = 0; kyy < 3; kyy++) {
                float xin[18];
                const float* rp = rowp + kyy * W_ + x0;
                xin[0] = (x0 == 0) ? 0.f : rp[-1];
#pragma unroll
                for (int j = 0; j < 16; j += 4) {
                    float4 v = *(const float4*)(rp + j);
                    xin[1 + j] = v.x; xin[2 + j] = v.y; xin[3 + j] = v.z; xin[4 + j] = v.w;
                }
                xin[17] = (x0 + 16 >= W_) ? 0.f : rp[16];
                const int t0 = kyy * 3;
#pragma unroll
                for (int x = 0; x < 16; x++) {
                    acc0[x] += xin[x] * wa[t0] + xin[x + 1] * wa[t0 + 1] + xin[x + 2] * wa[t0 + 2];
                    acc1[x] += xin[x] * wb[t0] + xin[x + 1] * wb[t0 + 1] + xin[x + 2] * wb[t0 + 2];
                }
            }
        }
    }

    const float kv = kk[b * C_ + lane];
    const float b0v = cb[e0 * C_ + lane];
    const float b1v = cb[e1 * C_ + lane];
    const float kw0 = kv * w0, kw1 = kv * w1;
    const size_t obase = ((size_t)(b * C_ + lane) * H_ + h) * W_ + x0;
#pragma unroll
    for (int x = 0; x < 16; x += 4) {
        float4 iv = *(const float4*)(in + obase + x);
        float4 ov;
        ov.x = iv.x + fmaxf(acc0[x + 0] + b0v, 0.f) * kw0 + fmaxf(acc1[x + 0] + b1v, 0.f) * kw1;
        ov.y = iv.y + fmaxf(acc0[x + 1] + b0v, 0.f) * kw0 + fmaxf(acc1[x + 1] + b1v, 0.f) * kw1;
        ov.z = iv.z + fmaxf(acc0[x + 2] + b0v, 0.f) * kw0 + fmaxf(acc1[x + 2] + b1v, 0.f) * kw1;
        ov.w = iv.w + fmaxf(acc0[x + 3] + b0v, 0.f) * kw0 + fmaxf(acc1[x + 3] + b1v, 0.f) * kw1;
        *(float4*)(out + obase + x) = ov;
    }
}

extern "C" void kernel_launch(void* const* d_in, const int* in_sizes, int n_in,
                              void* d_out, int out_size, void* d_ws, size_t ws_size,
                              hipStream_t stream) {
    const float* inputs = (const float*)d_in[0];
    const float* k      = (const float*)d_in[1];
    const float* gate_w = (const float*)d_in[2];
    const float* gate_b = (const float*)d_in[3];
    const float* conv_w = (const float*)d_in[4];
    const float* conv_b = (const float*)d_in[5];
    float* out = (float*)d_out;
    char* wsb = (char*)d_ws;

    if (ws_size >= WS_NEEDED) {
        unsigned short* inT = (unsigned short*)wsb;
        unsigned short* wT  = (unsigned short*)(wsb + OFF_WT);
        float* pooled = (float*)(wsb + OFF_POOL);

        prep<<<(WT_ELEMS + 255) / 256, 256, 0, stream>>>(conv_w, wT, inT, pooled);
        tcvt_pool<<<B_ * H_ / 2, 256, 0, stream>>>(inputs, inT, pooled);
        conv_direct<<<B_ * H_, 256, 0, stream>>>(inputs, k, conv_b, gate_w, gate_b,
                                                 pooled, inT, wT, out);
    } else {
        float* ws = (float*)d_ws;
        float* wTf    = ws + FB_WT_OFF;
        float* pooled = ws + FB_POOLED_OFF;
        float* ewbuf  = ws + FB_EW_OFF;

        pool_kernel<<<B_ * C_, 256, 0, stream>>>(inputs, pooled);
        gate_kernel<<<1, 64, 0, stream>>>(pooled, gate_w, gate_b, ewbuf);
        wtr_kernel<<<(E_ * C_ * 9 * C_ + 255) / 256, 256, 0, stream>>>(conv_w, wTf);
        conv_fallback<<<B_ * H_, 512, 0, stream>>>(inputs, k, wTf, conv_b, ewbuf, out);
    }
}

// Round 4
// 118.827 us; speedup vs baseline: 2.6385x; 2.6385x over previous
//
#include <hip/hip_runtime.h>

typedef __attribute__((ext_vector_type(8))) short bfrag8;    // 8 bf16 (4 VGPRs)
typedef __attribute__((ext_vector_type(16))) float f32x16;   // 32x32 MFMA acc

#define B_ 16
#define C_ 64
#define H_ 128
#define W_ 128
#define E_ 4
#define HW_ (H_ * W_)

// rolling conv geometry
#define RG 8                    // output rows per block
#define NSLOT 66                // 64 px + 2 halo
#define PLANE (NSLOT * 16)      // 1056 B per 8ci-plane
#define ROWB (8 * PLANE)        // 8448 B per staged row

// ---- fast-path ws layout (bytes) ----
#define WT_ELEMS (4 * 9 * 64 * 64)             // 147,456 bf16
#define OFF_POOL (WT_ELEMS * 2)                // 294,912
#define OFF_EW   (OFF_POOL + 1024 * 4)
#define WS_NEEDED ((size_t)(OFF_EW + 64 * 4))

// ---- fallback ws layout (floats) ----
#define FB_WT_OFF 0
#define FB_POOLED_OFF 147456
#define FB_EW_OFF 148480

__device__ inline unsigned short f2bf(float f) {
    unsigned u = __builtin_bit_cast(unsigned, f);
    unsigned r = u + 0x7FFFu + ((u >> 16) & 1u);
    return (unsigned short)(r >> 16);
}

// ---------------- pool (per (b,c) block) + fused weight convert ----------------
__global__ __launch_bounds__(256) void pool_wcvt(const float* __restrict__ in,
                                                 const float* __restrict__ cw,
                                                 float* __restrict__ pooled,
                                                 unsigned short* __restrict__ wT) {
    // weight convert: [e][co][ci][3][3] -> [e][tap][co][ci], blocks 0..575
    if (blockIdx.x < 576) {
        const int idx = blockIdx.x * 256 + threadIdx.x;   // < 147456
        const int ci = idx & 63;
        int r = idx >> 6;
        const int co = r & 63; r >>= 6;
        const int tap = r % 9;
        const int e = r / 9;
        wT[idx] = f2bf(cw[(((e * C_ + co) * C_ + ci) * 9) + tap]);
    }
    // pool: mean over HW for this (b,c)
    const int bc = blockIdx.x;
    const float* p = in + (size_t)bc * HW_;
    float s = 0.f;
    for (int i = threadIdx.x; i < HW_ / 4; i += 256) {
        float4 v = ((const float4*)p)[i];
        s += v.x + v.y + v.z + v.w;
    }
    for (int off = 32; off; off >>= 1) s += __shfl_down(s, off);
    __shared__ float red[4];
    const int lane = threadIdx.x & 63, wv = threadIdx.x >> 6;
    if (lane == 0) red[wv] = s;
    __syncthreads();
    if (threadIdx.x == 0)
        pooled[bc] = (red[0] + red[1] + red[2] + red[3]) * (1.0f / (float)HW_);
}

// ---------------- gate ----------------
__global__ void gate_kernel(const float* __restrict__ pooled,
                            const float* __restrict__ gate_w,
                            const float* __restrict__ gate_b,
                            float* __restrict__ ew) {
    const int b = threadIdx.x;
    if (b >= B_) return;
    float lg[E_];
    for (int e = 0; e < E_; e++) {
        float s = gate_b[e];
        for (int c = 0; c < C_; c++) s += pooled[b * C_ + c] * gate_w[e * C_ + c];
        lg[e] = s;
    }
    float m = fmaxf(fmaxf(lg[0], lg[1]), fmaxf(lg[2], lg[3]));
    float ex[E_], sum = 0.f;
    for (int e = 0; e < E_; e++) { ex[e] = expf(lg[e] - m); sum += ex[e]; }
    for (int e = 0; e < E_; e++) ex[e] /= sum;
    int i1 = 0;
    for (int e = 1; e < E_; e++) if (ex[e] > ex[i1]) i1 = e;
    int i2 = -1;
    for (int e = 0; e < E_; e++) {
        if (e == i1) continue;
        if (i2 < 0 || ex[e] > ex[i2]) i2 = e;
    }
    for (int e = 0; e < E_; e++)
        ew[b * E_ + e] = (e == i1 || e == i2) ? ex[e] : 0.f;
}

// ---------------- conv: rolling 3-row LDS ring, direct NCHW fp32 input ----------------
__global__ __launch_bounds__(128) void conv_roll(const float* __restrict__ in,
                                                 const float* __restrict__ kk,
                                                 const float* __restrict__ cb,
                                                 const float* __restrict__ ew,
                                                 const unsigned short* __restrict__ wT,
                                                 float* __restrict__ out) {
    const int raw = blockIdx.x;                 // 512 blocks
    const int swz = (raw & 7) * 64 + (raw >> 3);  // XCD-bijective: 2 images per XCD
    const int b = swz >> 5;                     // 32 blocks per image
    const int rem = swz & 31;
    const int h0 = (rem >> 1) * RG;
    const int x0 = (rem & 1) * 64;
    const int tid = threadIdx.x;
    const int lane = tid & 63;
    const int wv = tid >> 6;                    // 0,1
    const int ln = lane & 31;
    const int lh = lane >> 5;
    const int co0 = wv * 32;
    const int slot_i = tid & 63;                // interior slot-1 (px = x0+slot_i)

    __shared__ __align__(16) char ring[3 * ROWB];   // 25,344 B

    // expert weights (uniform per image)
    int e0 = 0, e1 = 0; float w0 = 0.f, w1 = 0.f;
    {
        int found = 0;
        for (int e = 0; e < E_; e++) {
            float we = ew[b * E_ + e];
            if (we != 0.f) {
                if (!found) { e0 = e; w0 = we; found = 1; }
                else        { e1 = e; w1 = we; }
            }
        }
        if (w1 == 0.f) e1 = e0;
    }

    float pv[4][8];   // prefetched interior row (4 ci-chunks x 8)
    float hv[8];      // halo chunk (threads 0..15)

    auto PREFETCH = [&](int r) {
        const bool vr = ((unsigned)r < (unsigned)H_);
        const int rr = vr ? r : 0;
#pragma unroll
        for (int rep = 0; rep < 4; ++rep) {
            const int ch = rep * 2 + wv;
            const float* src = in + (((size_t)(b * C_ + ch * 8) * H_ + rr) * W_ + x0 + slot_i);
#pragma unroll
            for (int j = 0; j < 8; ++j) pv[rep][j] = vr ? src[(size_t)j * HW_] : 0.f;
        }
        if (tid < 16) {
            const int ch = tid >> 1;
            const int px = (tid & 1) ? (x0 + 64) : (x0 - 1);
            const bool ok = vr && px >= 0 && px < W_;
            const float* src = in + (((size_t)(b * C_ + ch * 8) * H_ + rr) * W_ + (ok ? px : 0));
#pragma unroll
            for (int j = 0; j < 8; ++j) hv[j] = ok ? src[(size_t)j * HW_] : 0.f;
        }
    };
    auto COMMIT = [&](int rs) {
        char* base = ring + rs * ROWB;
#pragma unroll
        for (int rep = 0; rep < 4; ++rep) {
            const int ch = rep * 2 + wv;
            bfrag8 f;
#pragma unroll
            for (int j = 0; j < 8; ++j) f[j] = (short)f2bf(pv[rep][j]);
            *(bfrag8*)(base + ch * PLANE + (slot_i + 1) * 16) = f;
        }
        if (tid < 16) {
            const int ch = tid >> 1;
            const int sl = (tid & 1) ? 65 : 0;
            bfrag8 f;
#pragma unroll
            for (int j = 0; j < 8; ++j) f[j] = (short)f2bf(hv[j]);
            *(bfrag8*)(base + ch * PLANE + sl * 16) = f;
        }
    };

    // prologue: rows h0-1, h0, h0+1 -> ring slots 0,1,2
    PREFETCH(h0 - 1); COMMIT(0);
    PREFETCH(h0);     COMMIT(1);
    PREFETCH(h0 + 1); COMMIT(2);
    __syncthreads();

    int m0 = 0, m1 = 1, m2 = 2;   // ring slots of rows (h+s-1, h+s, h+s+1)
    for (int s = 0; s < RG; ++s) {
        if (s + 1 < RG) PREFETCH(h0 + s + 2);   // loads in flight during MFMA phase

        f32x16 A00, A01, A10, A11;
#pragma unroll
        for (int i = 0; i < 16; i++) { A00[i] = 0.f; A01[i] = 0.f; A10[i] = 0.f; A11[i] = 0.f; }

#pragma unroll
        for (int ky = 0; ky < 3; ++ky) {
            const char* rb = ring + (ky == 0 ? m0 : (ky == 1 ? m1 : m2)) * ROWB;
#pragma unroll
            for (int kx = 0; kx < 3; ++kx) {
                const int tap = ky * 3 + kx;
                const unsigned short* wp0 = wT + (((e0 * 9 + tap) * 64 + co0 + ln) << 6) + lh * 8;
                const unsigned short* wp1 = wT + (((e1 * 9 + tap) * 64 + co0 + ln) << 6) + lh * 8;
#pragma unroll
                for (int kb = 0; kb < 4; ++kb) {
                    const int ch = kb * 2 + lh;
                    bfrag8 bA = *(const bfrag8*)(rb + ch * PLANE + (ln + kx) * 16);
                    bfrag8 bB = *(const bfrag8*)(rb + ch * PLANE + (ln + kx + 32) * 16);
                    bfrag8 a0 = *(const bfrag8*)(wp0 + kb * 16);
                    bfrag8 a1 = *(const bfrag8*)(wp1 + kb * 16);
                    A00 = __builtin_amdgcn_mfma_f32_32x32x16_bf16(a0, bA, A00, 0, 0, 0);
                    A01 = __builtin_amdgcn_mfma_f32_32x32x16_bf16(a0, bB, A01, 0, 0, 0);
                    A10 = __builtin_amdgcn_mfma_f32_32x32x16_bf16(a1, bA, A10, 0, 0, 0);
                    A11 = __builtin_amdgcn_mfma_f32_32x32x16_bf16(a1, bB, A11, 0, 0, 0);
                }
            }
        }

        // epilogue: out = in + relu(acc+b)*k*w   (D: col=lane&31=px, row=co)
        const int row = h0 + s;
#pragma unroll
        for (int rg = 0; rg < 16; ++rg) {
            const int co = co0 + (rg & 3) + 8 * (rg >> 2) + 4 * lh;
            const float kv = kk[b * C_ + co];
            const float f0 = kv * w0, f1 = kv * w1;
            const float bb0 = cb[e0 * C_ + co], bb1 = cb[e1 * C_ + co];
            const size_t base = ((size_t)(b * C_ + co) * H_ + row) * W_;
            {
                const int px = x0 + ln;
                out[base + px] = in[base + px] + fmaxf(A00[rg] + bb0, 0.f) * f0
                                              + fmaxf(A10[rg] + bb1, 0.f) * f1;
            }
            {
                const int px = x0 + 32 + ln;
                out[base + px] = in[base + px] + fmaxf(A01[rg] + bb0, 0.f) * f0
                                              + fmaxf(A11[rg] + bb1, 0.f) * f1;
            }
        }

        __syncthreads();                      // all waves done reading slot m0
        if (s + 1 < RG) COMMIT(m0);           // row h0+s+2 replaces row h0+s-1
        __syncthreads();
        const int t = m0; m0 = m1; m1 = m2; m2 = t;
    }
}

// ================= fallback (fp32 path, used only if ws too small) =================
#define CHUNK 32

__global__ __launch_bounds__(256) void pool_kernel(const float* __restrict__ in,
                                                   float* __restrict__ pooled) {
    const int bc = blockIdx.x;
    const float* p = in + (size_t)bc * HW_;
    float s = 0.f;
    for (int i = threadIdx.x; i < HW_ / 4; i += 256) {
        float4 v = ((const float4*)p)[i];
        s += v.x + v.y + v.z + v.w;
    }
    for (int off = 32; off; off >>= 1) s += __shfl_down(s, off);
    __shared__ float red[4];
    const int lane = threadIdx.x & 63, wv = threadIdx.x >> 6;
    if (lane == 0) red[wv] = s;
    __syncthreads();
    if (threadIdx.x == 0)
        pooled[bc] = (red[0] + red[1] + red[2] + red[3]) * (1.0f / (float)HW_);
}

__global__ __launch_bounds__(256) void wtr_kernel(const float* __restrict__ cw,
                                                  float* __restrict__ wT) {
    const int idx = blockIdx.x * 256 + threadIdx.x;
    if (idx >= E_ * C_ * 9 * C_) return;
    const int co = idx & 63;
    const int t2 = idx >> 6;
    const int tap = t2 % 9;
    const int t3 = t2 / 9;
    const int ci = t3 & 63;
    const int e = t3 >> 6;
    wT[idx] = cw[(((e * C_ + co) * C_ + ci) * 9) + tap];
}

__global__ __launch_bounds__(512) void conv_fallback(const float* __restrict__ in,
                                                     const float* __restrict__ kk,
                                                     const float* __restrict__ wT,
                                                     const float* __restrict__ cb,
                                                     const float* __restrict__ ew,
                                                     float* __restrict__ out) {
    const int bid = blockIdx.x;
    const int b = bid / H_;
    const int h = bid % H_;
    const int tid = threadIdx.x;
    const int lane = tid & 63;
    const int wv = tid >> 6;
    const int x0 = wv * 16;

    __shared__ float sIn[CHUNK * 3 * W_];

    float w0 = 0.f, w1 = 0.f;
    int e0 = 0, e1 = 0;
    {
        float we[E_];
#pragma unroll
        for (int e = 0; e < E_; e++) we[e] = ew[b * E_ + e];
        int found = 0;
        for (int e = 0; e < E_; e++) {
            if (we[e] != 0.f) {
                if (!found) { e0 = e; w0 = we[e]; found = 1; }
                else        { e1 = e; w1 = we[e]; }
            }
        }
        if (w1 == 0.f) e1 = e0;
    }

    float acc0[16], acc1[16];
#pragma unroll
    for (int i = 0; i < 16; i++) { acc0[i] = 0.f; acc1[i] = 0.f; }

    for (int cblk = 0; cblk < C_ / CHUNK; cblk++) {
        const int cbase = cblk * CHUNK;
        __syncthreads();
        for (int f = tid; f < CHUNK * 3 * W_ / 4; f += 512) {
            const int fi = f * 4;
            const int ci = fi / (3 * W_);
            const int rem = fi - ci * 3 * W_;
            const int kyy = rem / W_;
            const int x = rem - kyy * W_;
            const int hh = h + kyy - 1;
            float4 v = make_float4(0.f, 0.f, 0.f, 0.f);
            if (hh >= 0 && hh < H_)
                v = *(const float4*)(in + ((size_t)(b * C_ + cbase + ci) * H_ + hh) * W_ + x);
            *(float4*)(sIn + fi) = v;
        }
        __syncthreads();

        const float* wp0 = wT + (size_t)((e0 * C_ + cbase) * 9) * C_ + lane;
        const float* wp1 = wT + (size_t)((e1 * C_ + cbase) * 9) * C_ + lane;
        for (int ci = 0; ci < CHUNK; ci++) {
            float wa[9], wb[9];
#pragma unroll
            for (int t = 0; t < 9; t++) {
                wa[t] = wp0[(ci * 9 + t) * C_];
                wb[t] = wp1[(ci * 9 + t) * C_];
            }
            const float* rowp = sIn + ci * 3 * W_;
#pragma unroll
            for (int kyy = 0; kyy < 3; kyy++) {
                float xin[18];
                const float* rp = rowp + kyy * W_ + x0;
                xin[0] = (x0 == 0) ? 0.f : rp[-1];
#pragma unroll
                for (int j = 0; j < 16; j += 4) {
                    float4 v = *(const float4*)(rp + j);
                    xin[1 + j] = v.x; xin[2 + j] = v.y; xin[3 + j] = v.z; xin[4 + j] = v.w;
                }
                xin[17] = (x0 + 16 >= W_) ? 0.f : rp[16];
                const int t0 = kyy * 3;
#pragma unroll
                for (int x = 0; x < 16; x++) {
                    acc0[x] += xin[x] * wa[t0] + xin[x + 1] * wa[t0 + 1] + xin[x + 2] * wa[t0 + 2];
                    acc1[x] += xin[x] * wb[t0] + xin[x + 1] * wb[t0 + 1] + xin[x + 2] * wb[t0 + 2];
                }
            }
        }
    }

    const float kv = kk[b * C_ + lane];
    const float b0v = cb[e0 * C_ + lane];
    const float b1v = cb[e1 * C_ + lane];
    const float kw0 = kv * w0, kw1 = kv * w1;
    const size_t obase = ((size_t)(b * C_ + lane) * H_ + h) * W_ + x0;
#pragma unroll
    for (int x = 0; x < 16; x += 4) {
        float4 iv = *(const float4*)(in + obase + x);
        float4 ov;
        ov.x = iv.x + fmaxf(acc0[x + 0] + b0v, 0.f) * kw0 + fmaxf(acc1[x + 0] + b1v, 0.f) * kw1;
        ov.y = iv.y + fmaxf(acc0[x + 1] + b0v, 0.f) * kw0 + fmaxf(acc1[x + 1] + b1v, 0.f) * kw1;
        ov.z = iv.z + fmaxf(acc0[x + 2] + b0v, 0.f) * kw0 + fmaxf(acc1[x + 2] + b1v, 0.f) * kw1;
        ov.w = iv.w + fmaxf(acc0[x + 3] + b0v, 0.f) * kw0 + fmaxf(acc1[x + 3] + b1v, 0.f) * kw1;
        *(float4*)(out + obase + x) = ov;
    }
}

extern "C" void kernel_launch(void* const* d_in, const int* in_sizes, int n_in,
                              void* d_out, int out_size, void* d_ws, size_t ws_size,
                              hipStream_t stream) {
    const float* inputs = (const float*)d_in[0];
    const float* k      = (const float*)d_in[1];
    const float* gate_w = (const float*)d_in[2];
    const float* gate_b = (const float*)d_in[3];
    const float* conv_w = (const float*)d_in[4];
    const float* conv_b = (const float*)d_in[5];
    float* out = (float*)d_out;
    char* wsb = (char*)d_ws;

    if (ws_size >= WS_NEEDED) {
        unsigned short* wT = (unsigned short*)wsb;
        float* pooled = (float*)(wsb + OFF_POOL);
        float* ewbuf  = (float*)(wsb + OFF_EW);

        pool_wcvt<<<B_ * C_, 256, 0, stream>>>(inputs, conv_w, pooled, wT);
        gate_kernel<<<1, 64, 0, stream>>>(pooled, gate_w, gate_b, ewbuf);
        conv_roll<<<512, 128, 0, stream>>>(inputs, k, conv_b, ewbuf, wT, out);
    } else {
        float* ws = (float*)d_ws;
        float* wTf    = ws + FB_WT_OFF;
        float* pooled = ws + FB_POOLED_OFF;
        float* ewbuf  = ws + FB_EW_OFF;

        pool_kernel<<<B_ * C_, 256, 0, stream>>>(inputs, pooled);
        gate_kernel<<<1, 64, 0, stream>>>(pooled, gate_w, gate_b, ewbuf);
        wtr_kernel<<<(E_ * C_ * 9 * C_ + 255) / 256, 256, 0, stream>>>(conv_w, wTf);
        conv_fallback<<<B_ * H_, 512, 0, stream>>>(inputs, k, wTf, conv_b, ewbuf, out);
    }
}